// Round 9
// baseline (502.780 us; speedup 1.0000x reference)
//
#include <hip/hip_runtime.h>
#include <hip/hip_bf16.h>
#include <cstdint>

// ---------------- problem constants ----------------
#define KNB      17          // 1+K neighbors
#define CH       53          // rppe channels
#define MP       16          // points per block (kernel A)
#define BM       64          // points per block (kernel B)
#define NTHR     512         // 8 waves
#define NRT      17          // row tiles in A = MP*KNB/16
#define SE_LD    72          // se LDS row stride (bf16)
#define CATW     1120        // cat global row width: [att 1088 | pc 2 | pad 30]
#define RES_LD   552         // res LDS row stride (bf16), 16B-aligned rows
#define NCHUNK   18          // ceil(35 ks / 2)
#define AST_LD   36          // astage padded row stride (ushort): 72B rows -> 2-way banks

// packed bf16 B-fragment segments in d_ws (ushort element offsets)
// fragment packing (A and B operands use the same k-major layout):
//   elem(ks, nt, lane l, jj)  <->  W[k = 32*ks + 8*(l>>4) + jj][col = 16*nt + (l&15)]
#define NE_CONV  (35*34*512)
#define NE_MLP   (2*2*512)
#define NE_ATT   (2*4*512)
#define NE_SKIP  (2*2*512)
#define WS_MLP   (NE_CONV)
#define WS_ATT   (WS_MLP + NE_MLP)
#define WS_SKIP  (WS_ATT + NE_ATT)
#define WS_TOTAL (WS_SKIP + NE_SKIP)

typedef __bf16 bf16x8 __attribute__((ext_vector_type(8)));
typedef float  f32x4  __attribute__((ext_vector_type(4)));
typedef unsigned short u16x4 __attribute__((ext_vector_type(4)));
typedef unsigned short u16x8 __attribute__((ext_vector_type(8)));

__device__ __forceinline__ unsigned short f2b(float f) {
    union { __bf16 h; unsigned short u; } v; v.h = (__bf16)f; return v.u;  // HW RNE
}
__device__ __forceinline__ float b2f(unsigned short b) {
    union { unsigned u; float f; } v; v.u = ((unsigned)b) << 16;
    return v.f;
}

// ---------------- weight prep: f32 -> packed bf16 fragments ----------------
__global__ void seac_prep(const float* __restrict__ Wmlp, const float* __restrict__ Watt,
                          const float* __restrict__ Wconv, const float* __restrict__ Wskip,
                          unsigned short* __restrict__ ws)
{
    int i = blockIdx.x * 256 + threadIdx.x;
    if (i >= WS_TOTAL) return;
    float v;
    if (i < WS_MLP) {                       // conv: K=1090 (cat order [att|pc], pad 1120), N=544
        int idx = i;
        int jj = idx & 7, l = (idx >> 3) & 63, t = idx >> 9;
        int nt = t % 34, ks = t / 34;
        int k = 32*ks + 8*(l >> 4) + jj;    // storage k in cat order
        int o = 16*nt + (l & 15);
        int ok;
        if (k < 1088)       ok = k + 2;     // att block
        else if (k == 1088) ok = 0;         // pc x
        else if (k == 1089) ok = 1;         // pc y
        else                ok = -1;        // pad
        v = (ok >= 0) ? Wconv[ok*544 + o] : 0.f;
    } else if (i < WS_ATT) {                // mlp: K=53 (pad 64), N=32
        int idx = i - WS_MLP;
        int jj = idx & 7, l = (idx >> 3) & 63, t = idx >> 9;
        int nt = t & 1, ks = t >> 1;
        int k = 32*ks + 8*(l >> 4) + jj;
        int o = 16*nt + (l & 15);
        v = (k < CH) ? Wmlp[k*32 + o] : 0.f;
    } else if (i < WS_SKIP) {               // att: K=64, N=64
        int idx = i - WS_ATT;
        int jj = idx & 7, l = (idx >> 3) & 63, t = idx >> 9;
        int nt = t & 3, ks = t >> 2;
        int k = 32*ks + 8*(l >> 4) + jj;
        int o = 16*nt + (l & 15);
        v = Watt[k*64 + o];
    } else {                                // skip: K=64 ([feats|res] order), N=32
        int idx = i - WS_SKIP;
        int jj = idx & 7, l = (idx >> 3) & 63, t = idx >> 9;
        int nt = t & 1, ks = t >> 1;
        int k = 32*ks + 8*(l >> 4) + jj;
        int o = 16*nt + (l & 15);
        v = Wskip[k*32 + o];
    }
    ws[i] = f2b(v);
}

// ---------------- kernel A: LocSE mlp + attention -> cat (global, row-major) ----------------
// LDS ~41.7 KB -> 3 blocks/CU   (measured ~113-120 us; unchanged)
__global__ __launch_bounds__(NTHR, 6) void seac_locse(
    const float* __restrict__ pc, const float* __restrict__ feats,
    const float* __restrict__ bmlp, const float* __restrict__ batt,
    const unsigned short* __restrict__ ws, unsigned short* __restrict__ catg,
    int pt0)
{
    __shared__ unsigned short se_l[272 * SE_LD];    // 39,168 B  rows p*17+j, cols [r(32)|feats(32)] -> att
    __shared__ float pcl[MP][KNB][2];               //  2,176 B
    __shared__ float bmlp_l[32];
    __shared__ float batt_l[64];

    const int tid  = threadIdx.x;
    const int w    = tid >> 6;
    const int l    = tid & 63;
    const int g    = l >> 4;
    const int c15  = l & 15;
    const long pbase = (long)pt0 + (long)blockIdx.x * MP;
    const bf16x8* wsB8 = (const bf16x8*)ws;

    // ---- phase 0: pc cache, feats->se[:,32:64], biases ----
    if (tid < MP*KNB) {
        int p = tid / KNB, i = tid - p*KNB;
        float x = pc[(pbase + p)*(KNB*2) + 2*i];
        float y = pc[(pbase + p)*(KNB*2) + 2*i + 1];
        pcl[p][i][0] = x; pcl[p][i][1] = y;
    }
    for (int q = tid; q < MP*544/4; q += NTHR) {            // 2176 quads
        float4 f = *(const float4*)&feats[pbase*544 + 4*q];
        int e0 = 4*q; int p = e0 / 544; int rem = e0 - 544*p;
        int j = rem >> 5, c = rem & 31;
        u16x4 u; u[0] = f2b(f.x); u[1] = f2b(f.y); u[2] = f2b(f.z); u[3] = f2b(f.w);
        *(u16x4*)&se_l[(p*KNB + j)*SE_LD + 32 + c] = u;
    }
    if (tid < 32)                     bmlp_l[tid]      = bmlp[tid];
    else if (tid >= 64 && tid < 128)  batt_l[tid-64]   = batt[tid-64];
    __syncthreads();

    // ---- phase 1 (swapped): r = relu(rppe @ W_mlp + b) -> se[:,0:32] ----
    {
        bf16x8 Bm[2][2];
        #pragma unroll
        for (int ks = 0; ks < 2; ++ks)
            #pragma unroll
            for (int nt = 0; nt < 2; ++nt)
                Bm[ks][nt] = wsB8[(WS_MLP >> 3) + (ks*2 + nt)*64 + l];
        float bch[2][4];
        #pragma unroll
        for (int nt = 0; nt < 2; ++nt)
            #pragma unroll
            for (int r = 0; r < 4; ++r) bch[nt][r] = bmlp_l[16*nt + 4*g + r];

        for (int mt = w; mt < NRT; mt += 8) {
            int row = 16*mt + c15;
            int p = row / KNB, j = row - p*KNB;
            float pjx = pcl[p][j][0], pjy = pcl[p][j][1];
            float nj = sqrtf(pjx*pjx + pjy*pjy);
            f32x4 acc0 = {0.f,0.f,0.f,0.f}, acc1 = {0.f,0.f,0.f,0.f};
            #pragma unroll
            for (int ks = 0; ks < 2; ++ks) {
                union { unsigned short u[8]; bf16x8 v; } a;
                #pragma unroll
                for (int jj = 0; jj < 8; ++jj) {
                    int k = 32*ks + 8*g + jj;
                    float vv;
                    if (k == 0) vv = pjx;
                    else if (k == 1) vv = pjy;
                    else if (k < CH) {
                        int kk = k - 2, ii = kk/3, t3 = kk - 3*ii;
                        vv = (t3 == 0) ? (pcl[p][ii][0] - pjx)
                           : (t3 == 1) ? (pcl[p][ii][1] - pjy) : nj;
                    } else vv = 0.f;
                    a.u[jj] = f2b(vv);
                }
                acc0 = __builtin_amdgcn_mfma_f32_16x16x32_bf16(Bm[ks][0], a.v, acc0, 0, 0, 0);
                acc1 = __builtin_amdgcn_mfma_f32_16x16x32_bf16(Bm[ks][1], a.v, acc1, 0, 0, 0);
            }
            u16x4 o0, o1;
            #pragma unroll
            for (int r = 0; r < 4; ++r) {
                o0[r] = f2b(fmaxf(acc0[r] + bch[0][r], 0.f));
                o1[r] = f2b(fmaxf(acc1[r] + bch[1][r], 0.f));
            }
            *(u16x4*)&se_l[row*SE_LD + 4*g]      = o0;
            *(u16x4*)&se_l[row*SE_LD + 16 + 4*g] = o1;
        }
    }
    __syncthreads();

    // ---- phase 2 (swapped): att = softmax(se @ W_att + b) * se -> se_l in place ----
    {
        bf16x8 Ba[2][4];
        #pragma unroll
        for (int ks = 0; ks < 2; ++ks)
            #pragma unroll
            for (int nt = 0; nt < 4; ++nt)
                Ba[ks][nt] = wsB8[(WS_ATT >> 3) + (ks*4 + nt)*64 + l];
        float bch[16];
        #pragma unroll
        for (int nt = 0; nt < 4; ++nt)
            #pragma unroll
            for (int r = 0; r < 4; ++r) bch[4*nt+r] = batt_l[16*nt + 4*g + r];

        for (int mt = w; mt < NRT; mt += 8) {
            int row = 16*mt + c15;
            bf16x8 b0 = *(const bf16x8*)&se_l[row*SE_LD + 8*g];
            bf16x8 b1 = *(const bf16x8*)&se_l[row*SE_LD + 32 + 8*g];
            f32x4 acc[4];
            #pragma unroll
            for (int nt = 0; nt < 4; ++nt) {
                f32x4 z = {0.f,0.f,0.f,0.f};
                acc[nt] = __builtin_amdgcn_mfma_f32_16x16x32_bf16(Ba[0][nt], b0, z,       0, 0, 0);
                acc[nt] = __builtin_amdgcn_mfma_f32_16x16x32_bf16(Ba[1][nt], b1, acc[nt], 0, 0, 0);
            }
            float vv[16];
            #pragma unroll
            for (int nt = 0; nt < 4; ++nt)
                #pragma unroll
                for (int r = 0; r < 4; ++r) vv[4*nt+r] = acc[nt][r] + bch[4*nt+r];
            float m = vv[0];
            #pragma unroll
            for (int i = 1; i < 16; ++i) m = fmaxf(m, vv[i]);
            m = fmaxf(m, __shfl_xor(m, 16)); m = fmaxf(m, __shfl_xor(m, 32));
            float s = 0.f;
            #pragma unroll
            for (int i = 0; i < 16; ++i) { vv[i] = __expf(vv[i] - m); s += vv[i]; }
            s += __shfl_xor(s, 16); s += __shfl_xor(s, 32);
            float inv = 1.f / s;
            #pragma unroll
            for (int nt = 0; nt < 4; ++nt) {
                u16x4 sv = *(const u16x4*)&se_l[row*SE_LD + 16*nt + 4*g];
                u16x4 ov;
                #pragma unroll
                for (int r = 0; r < 4; ++r) ov[r] = f2b(vv[4*nt+r]*inv * b2f(sv[r]));
                *(u16x4*)&se_l[row*SE_LD + 16*nt + 4*g] = ov;   // in place
            }
        }
    }
    __syncthreads();

    // ---- phase 3: bulk coalesced copy se_l -> catg (16B/lane), incl pc+pad tail ----
    for (int c = tid; c < MP*140; c += NTHR) {              // 140 u16x8 chunks per point
        int p = c / 140, rem = c - 140*p;
        int e = 8*rem;
        u16x8 v;
        if (e < 1088) {
            int row = p*KNB + (e >> 6), col = e & 63;
            v = *(const u16x8*)&se_l[row*SE_LD + col];
        } else {
            #pragma unroll
            for (int q = 0; q < 8; ++q) v[q] = 0;
            if (e == 1088) { v[0] = f2b(pcl[p][0][0]); v[1] = f2b(pcl[p][0][1]); }
        }
        *(u16x8*)&catg[(pbase + p)*CATW + e] = v;
    }
}

// ---------------- kernel B: conv GEMM (T14 reg-staged, raw barriers) + fused skip ----------------
// LDS = 36864 (astage dbuf, padded rows) + 35328 (res half) + 2176 = 74,368 B -> 2 blocks/CU
// Key: ds_write staging (not global_load_lds) => pre-barrier drain is lgkmcnt(0) only;
// B-weight prefetches survive the barrier (vmcnt never forced to 0 in the K-loop).
__global__ __launch_bounds__(NTHR, 4) void seac_conv(
    const unsigned short* __restrict__ catg, const float* __restrict__ feats,
    const float* __restrict__ bconv, const float* __restrict__ bskip,
    const unsigned short* __restrict__ ws, float* __restrict__ out, int pt0)
{
    __shared__ unsigned short astage[2][2][BM][AST_LD]; // 36,864 B  (72B rows: 2-way banks)
    __shared__ unsigned short res_l[32 * RES_LD];       // 35,328 B  (half the points at a time)
    __shared__ float bconv_l[544];                      //  2,176 B

    const int tid  = threadIdx.x;
    const int w    = tid >> 6;
    const int l    = tid & 63;
    const int g    = l >> 4;
    const int c15  = l & 15;
    const long pbase = (long)pt0 + (long)blockIdx.x * BM;
    const bf16x8* wsB8 = (const bf16x8*)ws;

    for (int i = tid; i < 544; i += NTHR) bconv_l[i] = bconv[i];

    // staging coords: thread owns granule (ksl = tid>>8, p = (tid>>2)&63, gr = tid&3)
    const int s_ksl = tid >> 8, s_p = (tid >> 2) & 63, s_gr = tid & 3;
    const unsigned short* s_src = &catg[(pbase + s_p)*CATW + 8*s_gr];

    // prologue: chunk0 -> LDS buf0; chunk1 -> regs
    {
        u16x8 r0 = *(const u16x8*)(s_src + 32*(0 + s_ksl));
        *(u16x8*)&astage[0][s_ksl][s_p][8*s_gr] = r0;
    }
    u16x8 rcur = *(const u16x8*)(s_src + 32*(2 + s_ksl));
    __syncthreads();

    f32x4 acc[4][5];
    #pragma unroll
    for (int mt = 0; mt < 4; ++mt)
        #pragma unroll
        for (int t = 0; t < 5; ++t) { f32x4 z = {0.f,0.f,0.f,0.f}; acc[mt][t] = z; }

    #pragma unroll 2
    for (int c = 0; c < NCHUNK; ++c) {
        // issue next-next chunk loads early (HBM/L3 latency hides under 2 iters)
        u16x8 rnext;
        if (c + 2 < NCHUNK) {
            int ksx = 2*(c+2) + s_ksl; if (ksx > 34) ksx = 0;   // clamp (pad ks)
            rnext = *(const u16x8*)(s_src + 32*ksx);
        }
        // write chunk c+1 into buf (c+1)&1 (its last reader finished before the
        // barrier that ended iter c-1)
        if (c + 1 < NCHUNK)
            *(u16x8*)&astage[(c+1)&1][s_ksl][s_p][8*s_gr] = rcur;

        // compute chunk c from astage[c&1]
        #pragma unroll
        for (int ksl = 0; ksl < 2; ++ksl) {
            int ks = 2*c + ksl;
            if (ks < 35) {
                bf16x8 a[4];
                #pragma unroll
                for (int mt = 0; mt < 4; ++mt)
                    a[mt] = *(const bf16x8*)&astage[c&1][ksl][16*mt + c15][8*g];
                #pragma unroll
                for (int t = 0; t < 5; ++t) {
                    int nt = w + 8*t;
                    if (nt < 34) {
                        bf16x8 b = wsB8[(ks*34 + nt)*64 + l];
                        #pragma unroll
                        for (int mt = 0; mt < 4; ++mt)
                            acc[mt][t] = __builtin_amdgcn_mfma_f32_16x16x32_bf16(a[mt], b, acc[mt][t], 0, 0, 0);
                    }
                }
            }
        }
        rcur = rnext;
        // drain LDS ops only; B-weight vmcnt prefetches stay in flight
        asm volatile("s_waitcnt lgkmcnt(0)" ::: "memory");
        __builtin_amdgcn_s_barrier();
        __builtin_amdgcn_sched_barrier(0);
    }

    __syncthreads();

    // skip weights + biases (registers)
    bf16x8 Bs[2][2];
    #pragma unroll
    for (int ks = 0; ks < 2; ++ks)
        #pragma unroll
        for (int nt = 0; nt < 2; ++nt)
            Bs[ks][nt] = wsB8[(WS_SKIP >> 3) + (ks*2 + nt)*64 + l];
    float bs0 = bskip[c15], bs1 = bskip[16 + c15];

    // two passes over point halves: write res half -> skip GEMM for that half
    #pragma unroll
    for (int half = 0; half < 2; ++half) {
        // conv epilogue: relu(acc+bias) -> res_l (rows = local point 0..31)
        #pragma unroll
        for (int t = 0; t < 5; ++t) {
            int nt = w + 8*t;
            if (nt < 34) {
                float bc = bconv_l[16*nt + c15];
                #pragma unroll
                for (int mh = 0; mh < 2; ++mh) {
                    int mt = 2*half + mh;
                    #pragma unroll
                    for (int r = 0; r < 4; ++r)
                        res_l[(16*mh + 4*g + r)*RES_LD + 16*nt + c15] =
                            f2b(fmaxf(acc[mt][t][r] + bc, 0.f));
                }
            }
        }
        __syncthreads();

        // skip: out = relu([feats|res] @ W_skip + b) for rows [544*half, 544*half+544)
        const long gofs = pbase*KNB + 544*half;
        for (int tt = 0; tt < 5; ++tt) {
            int mt2 = w + 8*tt;
            if (mt2 < 34) {
                int rr = 16*mt2 + c15;
                int pp = rr / 17, jn = rr - 17*pp;          // pp = local point 0..31
                float4 f0 = *(const float4*)&feats[(gofs + rr)*32 + 8*g];
                float4 f1 = *(const float4*)&feats[(gofs + rr)*32 + 8*g + 4];
                union { unsigned short u[8]; bf16x8 v; } af;
                af.u[0]=f2b(f0.x); af.u[1]=f2b(f0.y); af.u[2]=f2b(f0.z); af.u[3]=f2b(f0.w);
                af.u[4]=f2b(f1.x); af.u[5]=f2b(f1.y); af.u[6]=f2b(f1.z); af.u[7]=f2b(f1.w);
                bf16x8 ar = *(const bf16x8*)&res_l[pp*RES_LD + 32*jn + 8*g];
                f32x4 z = {0.f,0.f,0.f,0.f};
                f32x4 a0 = __builtin_amdgcn_mfma_f32_16x16x32_bf16(af.v, Bs[0][0], z, 0, 0, 0);
                a0       = __builtin_amdgcn_mfma_f32_16x16x32_bf16(ar,   Bs[1][0], a0, 0, 0, 0);
                f32x4 a1 = __builtin_amdgcn_mfma_f32_16x16x32_bf16(af.v, Bs[0][1], z, 0, 0, 0);
                a1       = __builtin_amdgcn_mfma_f32_16x16x32_bf16(ar,   Bs[1][1], a1, 0, 0, 0);
                #pragma unroll
                for (int r = 0; r < 4; ++r) {
                    long orow = gofs + 16*mt2 + 4*g + r;
                    out[orow*32 + c15]      = fmaxf(a0[r] + bs0, 0.f);
                    out[orow*32 + 16 + c15] = fmaxf(a1[r] + bs1, 0.f);
                }
            }
        }
        if (half == 0) __syncthreads();     // res_l reuse for second half
    }
}

extern "C" void kernel_launch(void* const* d_in, const int* in_sizes, int n_in,
                              void* d_out, int out_size, void* d_ws, size_t ws_size,
                              hipStream_t stream)
{
    const float* pc    = (const float*)d_in[0];
    const float* feats = (const float*)d_in[1];
    const float* Wmlp  = (const float*)d_in[2];
    const float* bmlp  = (const float*)d_in[3];
    const float* Watt  = (const float*)d_in[4];
    const float* batt  = (const float*)d_in[5];
    const float* Wconv = (const float*)d_in[6];
    const float* bconv = (const float*)d_in[7];
    const float* Wskip = (const float*)d_in[8];
    const float* bskip = (const float*)d_in[9];
    float* out = (float*)d_out;
    unsigned short* ws16 = (unsigned short*)d_ws;

    int npts = in_sizes[0] / (KNB*2);               // B*N = 65536

    // cat scratch lives after the weight fragments in d_ws; chunk by available size
    size_t frag_bytes = (size_t)WS_TOTAL * 2;
    size_t cat_off    = (frag_bytes + 255) & ~(size_t)255;
    unsigned short* catg = (unsigned short*)((char*)d_ws + cat_off);
    size_t avail = (ws_size > cat_off) ? (ws_size - cat_off) : 0;
    long maxpts = (long)(avail / (CATW * 2));
    long chunk  = (maxpts / BM) * BM;
    if (chunk > npts) chunk = npts;
    if (chunk < BM)   chunk = BM;                   // assume ws_size >= ~2.5 MB

    int prep_blocks = (WS_TOTAL + 255) / 256;
    hipLaunchKernelGGL(seac_prep, dim3(prep_blocks), dim3(256), 0, stream,
                       Wmlp, Watt, Wconv, Wskip, ws16);

    for (long base = 0; base < npts; base += chunk) {
        long c = npts - base; if (c > chunk) c = chunk;
        hipLaunchKernelGGL(seac_locse, dim3((int)(c / MP)), dim3(NTHR), 0, stream,
                           pc, feats, bmlp, batt, ws16, catg, (int)base);
        hipLaunchKernelGGL(seac_conv, dim3((int)(c / BM)), dim3(NTHR), 0, stream,
                           catg, feats, bconv, bskip, ws16, out, (int)base);
    }
}

// Round 10
// 307.300 us; speedup vs baseline: 1.6361x; 1.6361x over previous
//
#include <hip/hip_runtime.h>
#include <hip/hip_bf16.h>
#include <cstdint>

// ---------------- problem constants ----------------
#define KNB      17          // 1+K neighbors
#define CH       53          // rppe channels
#define MP       16          // points per block (kernel A)
#define BM       128         // points per block (kernel B)
#define NTHR     512         // 8 waves
#define NRT      17          // row tiles in A = MP*KNB/16
#define SE_LD    72          // se LDS row stride (bf16)
#define CATW     1120        // cat global row width: [att 1088 | pc 2 | pad 30]
#define RES_LD   552         // res LDS row stride (bf16), 16B-aligned rows
#define NCHUNK   18          // ceil(35 ks / 2)

// packed bf16 B-fragment segments in d_ws (ushort element offsets)
// fragment packing (A and B operands use the same k-major layout):
//   elem(ks, nt, lane l, jj)  <->  W[k = 32*ks + 8*(l>>4) + jj][col = 16*nt + (l&15)]
#define NE_CONV  (35*34*512)
#define NE_MLP   (2*2*512)
#define NE_ATT   (2*4*512)
#define NE_SKIP  (2*2*512)
#define WS_MLP   (NE_CONV)
#define WS_ATT   (WS_MLP + NE_MLP)
#define WS_SKIP  (WS_ATT + NE_ATT)
#define WS_TOTAL (WS_SKIP + NE_SKIP)

typedef __bf16 bf16x8 __attribute__((ext_vector_type(8)));
typedef float  f32x4  __attribute__((ext_vector_type(4)));
typedef unsigned short u16x4 __attribute__((ext_vector_type(4)));
typedef unsigned short u16x8 __attribute__((ext_vector_type(8)));

__device__ __forceinline__ unsigned short f2b(float f) {
    union { __bf16 h; unsigned short u; } v; v.h = (__bf16)f; return v.u;  // HW RNE
}
__device__ __forceinline__ float b2f(unsigned short b) {
    union { unsigned u; float f; } v; v.u = ((unsigned)b) << 16;
    return v.f;
}
__device__ __forceinline__ void gload_lds16(const void* g, void* l) {
    __builtin_amdgcn_global_load_lds(
        (const __attribute__((address_space(1))) unsigned int*)g,
        (__attribute__((address_space(3))) unsigned int*)l, 16, 0, 0);
}

// ---------------- weight prep: f32 -> packed bf16 fragments ----------------
__global__ void seac_prep(const float* __restrict__ Wmlp, const float* __restrict__ Watt,
                          const float* __restrict__ Wconv, const float* __restrict__ Wskip,
                          unsigned short* __restrict__ ws)
{
    int i = blockIdx.x * 256 + threadIdx.x;
    if (i >= WS_TOTAL) return;
    float v;
    if (i < WS_MLP) {                       // conv: K=1090 (cat order [att|pc], pad 1120), N=544
        int idx = i;
        int jj = idx & 7, l = (idx >> 3) & 63, t = idx >> 9;
        int nt = t % 34, ks = t / 34;
        int k = 32*ks + 8*(l >> 4) + jj;    // storage k in cat order
        int o = 16*nt + (l & 15);
        int ok;
        if (k < 1088)       ok = k + 2;     // att block
        else if (k == 1088) ok = 0;         // pc x
        else if (k == 1089) ok = 1;         // pc y
        else                ok = -1;        // pad
        v = (ok >= 0) ? Wconv[ok*544 + o] : 0.f;
    } else if (i < WS_ATT) {                // mlp: K=53 (pad 64), N=32
        int idx = i - WS_MLP;
        int jj = idx & 7, l = (idx >> 3) & 63, t = idx >> 9;
        int nt = t & 1, ks = t >> 1;
        int k = 32*ks + 8*(l >> 4) + jj;
        int o = 16*nt + (l & 15);
        v = (k < CH) ? Wmlp[k*32 + o] : 0.f;
    } else if (i < WS_SKIP) {               // att: K=64, N=64
        int idx = i - WS_ATT;
        int jj = idx & 7, l = (idx >> 3) & 63, t = idx >> 9;
        int nt = t & 3, ks = t >> 2;
        int k = 32*ks + 8*(l >> 4) + jj;
        int o = 16*nt + (l & 15);
        v = Watt[k*64 + o];
    } else {                                // skip: K=64 ([feats|res] order), N=32
        int idx = i - WS_SKIP;
        int jj = idx & 7, l = (idx >> 3) & 63, t = idx >> 9;
        int nt = t & 1, ks = t >> 1;
        int k = 32*ks + 8*(l >> 4) + jj;
        int o = 16*nt + (l & 15);
        v = Wskip[k*32 + o];
    }
    ws[i] = f2b(v);
}

// ---------------- kernel A: LocSE mlp + attention -> cat (global, row-major) ----------------
// LDS ~41.7 KB -> 3 blocks/CU   (measured ~113-120 us; unchanged)
__global__ __launch_bounds__(NTHR, 6) void seac_locse(
    const float* __restrict__ pc, const float* __restrict__ feats,
    const float* __restrict__ bmlp, const float* __restrict__ batt,
    const unsigned short* __restrict__ ws, unsigned short* __restrict__ catg,
    int pt0)
{
    __shared__ unsigned short se_l[272 * SE_LD];    // 39,168 B  rows p*17+j, cols [r(32)|feats(32)] -> att
    __shared__ float pcl[MP][KNB][2];               //  2,176 B
    __shared__ float bmlp_l[32];
    __shared__ float batt_l[64];

    const int tid  = threadIdx.x;
    const int w    = tid >> 6;
    const int l    = tid & 63;
    const int g    = l >> 4;
    const int c15  = l & 15;
    const long pbase = (long)pt0 + (long)blockIdx.x * MP;
    const bf16x8* wsB8 = (const bf16x8*)ws;

    // ---- phase 0: pc cache, feats->se[:,32:64], biases ----
    if (tid < MP*KNB) {
        int p = tid / KNB, i = tid - p*KNB;
        float x = pc[(pbase + p)*(KNB*2) + 2*i];
        float y = pc[(pbase + p)*(KNB*2) + 2*i + 1];
        pcl[p][i][0] = x; pcl[p][i][1] = y;
    }
    for (int q = tid; q < MP*544/4; q += NTHR) {            // 2176 quads
        float4 f = *(const float4*)&feats[pbase*544 + 4*q];
        int e0 = 4*q; int p = e0 / 544; int rem = e0 - 544*p;
        int j = rem >> 5, c = rem & 31;
        u16x4 u; u[0] = f2b(f.x); u[1] = f2b(f.y); u[2] = f2b(f.z); u[3] = f2b(f.w);
        *(u16x4*)&se_l[(p*KNB + j)*SE_LD + 32 + c] = u;
    }
    if (tid < 32)                     bmlp_l[tid]      = bmlp[tid];
    else if (tid >= 64 && tid < 128)  batt_l[tid-64]   = batt[tid-64];
    __syncthreads();

    // ---- phase 1 (swapped): r = relu(rppe @ W_mlp + b) -> se[:,0:32] ----
    {
        bf16x8 Bm[2][2];
        #pragma unroll
        for (int ks = 0; ks < 2; ++ks)
            #pragma unroll
            for (int nt = 0; nt < 2; ++nt)
                Bm[ks][nt] = wsB8[(WS_MLP >> 3) + (ks*2 + nt)*64 + l];
        float bch[2][4];
        #pragma unroll
        for (int nt = 0; nt < 2; ++nt)
            #pragma unroll
            for (int r = 0; r < 4; ++r) bch[nt][r] = bmlp_l[16*nt + 4*g + r];

        for (int mt = w; mt < NRT; mt += 8) {
            int row = 16*mt + c15;
            int p = row / KNB, j = row - p*KNB;
            float pjx = pcl[p][j][0], pjy = pcl[p][j][1];
            float nj = sqrtf(pjx*pjx + pjy*pjy);
            f32x4 acc0 = {0.f,0.f,0.f,0.f}, acc1 = {0.f,0.f,0.f,0.f};
            #pragma unroll
            for (int ks = 0; ks < 2; ++ks) {
                union { unsigned short u[8]; bf16x8 v; } a;
                #pragma unroll
                for (int jj = 0; jj < 8; ++jj) {
                    int k = 32*ks + 8*g + jj;
                    float vv;
                    if (k == 0) vv = pjx;
                    else if (k == 1) vv = pjy;
                    else if (k < CH) {
                        int kk = k - 2, ii = kk/3, t3 = kk - 3*ii;
                        vv = (t3 == 0) ? (pcl[p][ii][0] - pjx)
                           : (t3 == 1) ? (pcl[p][ii][1] - pjy) : nj;
                    } else vv = 0.f;
                    a.u[jj] = f2b(vv);
                }
                acc0 = __builtin_amdgcn_mfma_f32_16x16x32_bf16(Bm[ks][0], a.v, acc0, 0, 0, 0);
                acc1 = __builtin_amdgcn_mfma_f32_16x16x32_bf16(Bm[ks][1], a.v, acc1, 0, 0, 0);
            }
            u16x4 o0, o1;
            #pragma unroll
            for (int r = 0; r < 4; ++r) {
                o0[r] = f2b(fmaxf(acc0[r] + bch[0][r], 0.f));
                o1[r] = f2b(fmaxf(acc1[r] + bch[1][r], 0.f));
            }
            *(u16x4*)&se_l[row*SE_LD + 4*g]      = o0;
            *(u16x4*)&se_l[row*SE_LD + 16 + 4*g] = o1;
        }
    }
    __syncthreads();

    // ---- phase 2 (swapped): att = softmax(se @ W_att + b) * se -> se_l in place ----
    {
        bf16x8 Ba[2][4];
        #pragma unroll
        for (int ks = 0; ks < 2; ++ks)
            #pragma unroll
            for (int nt = 0; nt < 4; ++nt)
                Ba[ks][nt] = wsB8[(WS_ATT >> 3) + (ks*4 + nt)*64 + l];
        float bch[16];
        #pragma unroll
        for (int nt = 0; nt < 4; ++nt)
            #pragma unroll
            for (int r = 0; r < 4; ++r) bch[4*nt+r] = batt_l[16*nt + 4*g + r];

        for (int mt = w; mt < NRT; mt += 8) {
            int row = 16*mt + c15;
            bf16x8 b0 = *(const bf16x8*)&se_l[row*SE_LD + 8*g];
            bf16x8 b1 = *(const bf16x8*)&se_l[row*SE_LD + 32 + 8*g];
            f32x4 acc[4];
            #pragma unroll
            for (int nt = 0; nt < 4; ++nt) {
                f32x4 z = {0.f,0.f,0.f,0.f};
                acc[nt] = __builtin_amdgcn_mfma_f32_16x16x32_bf16(Ba[0][nt], b0, z,       0, 0, 0);
                acc[nt] = __builtin_amdgcn_mfma_f32_16x16x32_bf16(Ba[1][nt], b1, acc[nt], 0, 0, 0);
            }
            float vv[16];
            #pragma unroll
            for (int nt = 0; nt < 4; ++nt)
                #pragma unroll
                for (int r = 0; r < 4; ++r) vv[4*nt+r] = acc[nt][r] + bch[4*nt+r];
            float m = vv[0];
            #pragma unroll
            for (int i = 1; i < 16; ++i) m = fmaxf(m, vv[i]);
            m = fmaxf(m, __shfl_xor(m, 16)); m = fmaxf(m, __shfl_xor(m, 32));
            float s = 0.f;
            #pragma unroll
            for (int i = 0; i < 16; ++i) { vv[i] = __expf(vv[i] - m); s += vv[i]; }
            s += __shfl_xor(s, 16); s += __shfl_xor(s, 32);
            float inv = 1.f / s;
            #pragma unroll
            for (int nt = 0; nt < 4; ++nt) {
                u16x4 sv = *(const u16x4*)&se_l[row*SE_LD + 16*nt + 4*g];
                u16x4 ov;
                #pragma unroll
                for (int r = 0; r < 4; ++r) ov[r] = f2b(vv[4*nt+r]*inv * b2f(sv[r]));
                *(u16x4*)&se_l[row*SE_LD + 16*nt + 4*g] = ov;   // in place
            }
        }
    }
    __syncthreads();

    // ---- phase 3: bulk coalesced copy se_l -> catg (16B/lane), incl pc+pad tail ----
    for (int c = tid; c < MP*140; c += NTHR) {              // 140 u16x8 chunks per point
        int p = c / 140, rem = c - 140*p;
        int e = 8*rem;
        u16x8 v;
        if (e < 1088) {
            int row = p*KNB + (e >> 6), col = e & 63;
            v = *(const u16x8*)&se_l[row*SE_LD + col];
        } else {
            #pragma unroll
            for (int q = 0; q < 8; ++q) v[q] = 0;
            if (e == 1088) { v[0] = f2b(pcl[p][0][0]); v[1] = f2b(pcl[p][0][1]); }
        }
        *(u16x8*)&catg[(pbase + p)*CATW + e] = v;
    }
}

// ---------------- kernel B: conv GEMM (BM=128, 2x B-reuse) + fused skip ----------------
// LDS = 32768 (astage dbuf) + 35328 (res quarter) + 2176 = 70,272 B
// acc[8][5] -> ~160 AGPR + ~80 VGPR -> 8 waves/CU (1 block); grid 512 (2 rounds).
// Staging source is XOR-swizzled so the (linear) gload_lds layout gives 2-way-free
// ds_read_b128 (slot s of row p holds granule s ^ ((p>>1)&3)) [rule #21: both sides].
__global__ __launch_bounds__(NTHR, 2) void seac_conv(
    const unsigned short* __restrict__ catg, const float* __restrict__ feats,
    const float* __restrict__ bconv, const float* __restrict__ bskip,
    const unsigned short* __restrict__ ws, float* __restrict__ out, int pt0)
{
    __shared__ unsigned short astage[2][2][BM][32];  // 32,768 B  A 2-ks chunk dbuf
    __shared__ unsigned short res_l[32 * RES_LD];    // 35,328 B  (quarter of the points)
    __shared__ float bconv_l[544];                   //  2,176 B

    const int tid  = threadIdx.x;
    const int w    = tid >> 6;
    const int l    = tid & 63;
    const int g    = l >> 4;
    const int c15  = l & 15;
    const long pbase = (long)pt0 + (long)blockIdx.x * BM;
    const bf16x8* wsB8 = (const bf16x8*)ws;

    for (int i = tid; i < 544; i += NTHR) bconv_l[i] = bconv[i];

    // staging: 1024 granules of 16B per 2-ks chunk, 2 per thread.
    // granule q: ksl=q>>9, p=(q>>2)&127, slot=q&3 holds global gr = slot ^ ((p>>1)&3).
    #define STAGE(c, b)                                                              \
        _Pragma("unroll")                                                            \
        for (int r2 = 0; r2 < 2; ++r2) {                                             \
            int q   = tid + 512*r2;                                                  \
            int ksl = q >> 9;                                                        \
            int ks_ = 2*(c) + ksl;                                                   \
            int p   = (q >> 2) & 127;                                                \
            int gr  = (q & 3) ^ ((p >> 1) & 3);                                      \
            if (ks_ < 35)                                                            \
                gload_lds16(&catg[(pbase + p)*CATW + 32*ks_ + 8*gr],                 \
                            &astage[b][0][0][0] + (size_t)q*8);                      \
        }

    STAGE(0, 0);
    __syncthreads();

    f32x4 acc[8][5];
    #pragma unroll
    for (int mt = 0; mt < 8; ++mt)
        #pragma unroll
        for (int t = 0; t < 5; ++t) { f32x4 z = {0.f,0.f,0.f,0.f}; acc[mt][t] = z; }

    int buf = 0;
    for (int c = 0; c < NCHUNK; ++c) {
        if (c + 1 < NCHUNK) STAGE(c+1, buf^1);
        #pragma unroll
        for (int ksl = 0; ksl < 2; ++ksl) {
            int ks = 2*c + ksl;
            if (ks < 35) {
                const int sw = g ^ ((c15 >> 1) & 3);     // swizzled chunk slot
                bf16x8 a[8];
                #pragma unroll
                for (int mt = 0; mt < 8; ++mt)
                    a[mt] = *(const bf16x8*)&astage[buf][ksl][16*mt + c15][8*sw];
                #pragma unroll
                for (int t = 0; t < 5; ++t) {
                    int nt = w + 8*t;
                    if (nt < 34) {
                        bf16x8 b = wsB8[(ks*34 + nt)*64 + l];
                        #pragma unroll
                        for (int mt = 0; mt < 8; ++mt)
                            acc[mt][t] = __builtin_amdgcn_mfma_f32_16x16x32_bf16(a[mt], b, acc[mt][t], 0, 0, 0);
                    }
                }
            }
        }
        __syncthreads();            // drains staging vmcnt + all reads of buf done
        buf ^= 1;
    }
    #undef STAGE

    // skip weights + biases (registers)
    bf16x8 Bs[2][2];
    #pragma unroll
    for (int ks = 0; ks < 2; ++ks)
        #pragma unroll
        for (int nt = 0; nt < 2; ++nt)
            Bs[ks][nt] = wsB8[(WS_SKIP >> 3) + (ks*2 + nt)*64 + l];
    float bs0 = bskip[c15], bs1 = bskip[16 + c15];

    // four passes over point quarters (32 pts = 544 rows each):
    // write res quarter -> skip GEMM for that quarter
    #pragma unroll
    for (int qh = 0; qh < 4; ++qh) {
        // conv epilogue: relu(acc+bias) -> res_l (rows = local point 0..31)
        #pragma unroll
        for (int t = 0; t < 5; ++t) {
            int nt = w + 8*t;
            if (nt < 34) {
                float bc = bconv_l[16*nt + c15];
                #pragma unroll
                for (int mh = 0; mh < 2; ++mh) {
                    int mt = 2*qh + mh;
                    #pragma unroll
                    for (int r = 0; r < 4; ++r)
                        res_l[(16*mh + 4*g + r)*RES_LD + 16*nt + c15] =
                            f2b(fmaxf(acc[mt][t][r] + bc, 0.f));
                }
            }
        }
        __syncthreads();

        // skip: out = relu([feats|res] @ W_skip + b) for rows [544*qh, 544*qh+544)
        const long gofs = pbase*KNB + 544*qh;
        for (int tt = 0; tt < 5; ++tt) {
            int mt2 = w + 8*tt;
            if (mt2 < 34) {
                int rr = 16*mt2 + c15;
                int pp = rr / 17, jn = rr - 17*pp;          // pp = local point 0..31
                float4 f0 = *(const float4*)&feats[(gofs + rr)*32 + 8*g];
                float4 f1 = *(const float4*)&feats[(gofs + rr)*32 + 8*g + 4];
                union { unsigned short u[8]; bf16x8 v; } af;
                af.u[0]=f2b(f0.x); af.u[1]=f2b(f0.y); af.u[2]=f2b(f0.z); af.u[3]=f2b(f0.w);
                af.u[4]=f2b(f1.x); af.u[5]=f2b(f1.y); af.u[6]=f2b(f1.z); af.u[7]=f2b(f1.w);
                bf16x8 ar = *(const bf16x8*)&res_l[pp*RES_LD + 32*jn + 8*g];
                f32x4 z = {0.f,0.f,0.f,0.f};
                f32x4 a0 = __builtin_amdgcn_mfma_f32_16x16x32_bf16(af.v, Bs[0][0], z, 0, 0, 0);
                a0       = __builtin_amdgcn_mfma_f32_16x16x32_bf16(ar,   Bs[1][0], a0, 0, 0, 0);
                f32x4 a1 = __builtin_amdgcn_mfma_f32_16x16x32_bf16(af.v, Bs[0][1], z, 0, 0, 0);
                a1       = __builtin_amdgcn_mfma_f32_16x16x32_bf16(ar,   Bs[1][1], a1, 0, 0, 0);
                #pragma unroll
                for (int r = 0; r < 4; ++r) {
                    long orow = gofs + 16*mt2 + 4*g + r;
                    out[orow*32 + c15]      = fmaxf(a0[r] + bs0, 0.f);
                    out[orow*32 + 16 + c15] = fmaxf(a1[r] + bs1, 0.f);
                }
            }
        }
        if (qh < 3) __syncthreads();        // res_l reuse for next quarter
    }
}

extern "C" void kernel_launch(void* const* d_in, const int* in_sizes, int n_in,
                              void* d_out, int out_size, void* d_ws, size_t ws_size,
                              hipStream_t stream)
{
    const float* pc    = (const float*)d_in[0];
    const float* feats = (const float*)d_in[1];
    const float* Wmlp  = (const float*)d_in[2];
    const float* bmlp  = (const float*)d_in[3];
    const float* Watt  = (const float*)d_in[4];
    const float* batt  = (const float*)d_in[5];
    const float* Wconv = (const float*)d_in[6];
    const float* bconv = (const float*)d_in[7];
    const float* Wskip = (const float*)d_in[8];
    const float* bskip = (const float*)d_in[9];
    float* out = (float*)d_out;
    unsigned short* ws16 = (unsigned short*)d_ws;

    int npts = in_sizes[0] / (KNB*2);               // B*N = 65536

    // cat scratch lives after the weight fragments in d_ws; chunk by available size
    size_t frag_bytes = (size_t)WS_TOTAL * 2;
    size_t cat_off    = (frag_bytes + 255) & ~(size_t)255;
    unsigned short* catg = (unsigned short*)((char*)d_ws + cat_off);
    size_t avail = (ws_size > cat_off) ? (ws_size - cat_off) : 0;
    long maxpts = (long)(avail / (CATW * 2));
    long chunk  = (maxpts / BM) * BM;
    if (chunk > npts) chunk = npts;
    if (chunk < BM)   chunk = BM;                   // assume ws_size >= ~2.5 MB

    int prep_blocks = (WS_TOTAL + 255) / 256;
    hipLaunchKernelGGL(seac_prep, dim3(prep_blocks), dim3(256), 0, stream,
                       Wmlp, Watt, Wconv, Wskip, ws16);

    for (long base = 0; base < npts; base += chunk) {
        long c = npts - base; if (c > chunk) c = chunk;
        hipLaunchKernelGGL(seac_locse, dim3((int)(c / MP)), dim3(NTHR), 0, stream,
                           pc, feats, bmlp, batt, ws16, catg, (int)base);
        hipLaunchKernelGGL(seac_conv, dim3((int)(c / BM)), dim3(NTHR), 0, stream,
                           catg, feats, bconv, bskip, ws16, out, (int)base);
    }
}